// Round 6
// baseline (735.412 us; speedup 1.0000x reference)
//
#include <hip/hip_runtime.h>
#include <math.h>
#include <stdint.h>

#define LOG2_T 19
#define T_SIZE (1u << LOG2_T)
#define T_MASK (T_SIZE - 1u)
#define N_LEVELS 16
#define N_CELL 5             // levels 0..4: cell tables (8 corners / 32B entry)
#define N_HASH 11            // levels 5..15: packed bf16 hash tables in tabF
#define PRIME1 2654435761u
#define PRIME2 805459861u

typedef unsigned long long u64;
typedef float f4v __attribute__((ext_vector_type(4)));

struct Params {
    int res[N_LEVELS];
    int dOff[N_CELL];        // dword offset of each cell-table level in tabD
    int cellOffC[N_CELL + 1];// cumulative cell counts (levels 0..4)
    int cellTot;
};

__device__ __forceinline__ float bf_lo(uint32_t v) { return __uint_as_float(v << 16); }
__device__ __forceinline__ float bf_hi(uint32_t v) { return __uint_as_float(v & 0xFFFF0000u); }

__device__ __forceinline__ uint32_t f32_to_bf16_rne(float f) {
    uint32_t u = __float_as_uint(f);
    u += 0x7FFFu + ((u >> 16) & 1u);
    return u >> 16;
}
__device__ __forceinline__ uint32_t pack2(float2 e) {
    return f32_to_bf16_rne(e.x) | (f32_to_bf16_rne(e.y) << 16);
}

__device__ __forceinline__ float2 nt_load_f2(const float2* p) {
    union { float2 f; u64 u; } cv;
    cv.u = __builtin_nontemporal_load((const u64*)p);
    return cv.f;
}
__device__ __forceinline__ void nt_store_f2(float2 v, float2* p) {
    union { float2 f; u64 u; } cv; cv.f = v;
    __builtin_nontemporal_store(cv.u, (u64*)p);
}

// select one dword of a quad by 2-bit index (pure VALU, no dynamic indexing)
__device__ __forceinline__ uint32_t sel4(uint4 q, uint32_t s) {
    const uint32_t a = (s & 1u) ? q.y : q.x;
    const uint32_t b = (s & 1u) ? q.w : q.z;
    return (s & 2u) ? b : a;
}

// ---------- build: hash tables (levels 5..15) fp32 -> packed bf16 ----------
__global__ __launch_bounds__(256) void hg_build_fine(
    const float2* __restrict__ emb, uint32_t* __restrict__ tabF)
{
    const int i = blockIdx.x * 256 + threadIdx.x;          // [0, N_HASH*T)
    tabF[i] = pack2(emb[(size_t)N_CELL * T_SIZE + i]);
}

// ---------- build: cell tables (levels 0..4): 8 corners per cell, 32B ----------
__global__ __launch_bounds__(256) void hg_build_cell(
    const float2* __restrict__ emb, uint32_t* __restrict__ tabD, Params P)
{
    const int i = blockIdx.x * 256 + threadIdx.x;          // one thread per dword
    if (i >= P.cellTot * 8) return;
    const int cg = i >> 3, k = i & 7;                      // cell, corner
    int l = 0;
    while (l < N_CELL - 1 && cg >= P.cellOffC[l + 1]) ++l;
    const int e = cg - P.cellOffC[l];
    const int C = P.res[l] - 1;
    const int ix = e % C; const int r = e / C; const int iy = r % C; const int iz = r / C;
    const uint32_t xx = (uint32_t)(ix + (k & 1));
    const uint32_t yy = (uint32_t)(iy + ((k >> 1) & 1));
    const uint32_t zz = (uint32_t)(iz + (k >> 2));
    const uint32_t h = (xx ^ (yy * PRIME1) ^ (zz * PRIME2)) & T_MASK;
    tabD[P.dOff[l] + e * 8 + k] = pack2(emb[(size_t)l * T_SIZE + h]);
}

// ---------- gather helpers ----------
struct Pt { int ix, iy, iz; float fx, fy, fz; };

__device__ __forceinline__ Pt mk_pt(float x0, float x1, float x2,
                                    int rl, float rf) {
    Pt p;
    const float sx = x0 * rf, sy = x1 * rf, sz = x2 * rf;
    int ix = (int)sx; ix = ix < 0 ? 0 : (ix > rl - 2 ? rl - 2 : ix);
    int iy = (int)sy; iy = iy < 0 ? 0 : (iy > rl - 2 ? rl - 2 : iy);
    int iz = (int)sz; iz = iz < 0 ? 0 : (iz > rl - 2 ? rl - 2 : iz);
    p.ix = ix; p.iy = iy; p.iz = iz;
    p.fx = sx - (float)ix; p.fy = sy - (float)iy; p.fz = sz - (float)iz;
    return p;
}

struct C8 { uint32_t c0, c1, c2, c3, c4, c5, c6, c7; };

// hash gather via aligned quads. h(x+1) = h(x) ^ dx with dx = x^(x+1).
// 4 dwordx4 (one per (dy,dz) combo) + 4 UNCONDITIONAL dwords at i^dx.
// dx<4 (75%): the dword hits the same 16B line (L1-fast); dx>=4: it is the
// needed second x-corner line. No divergent branch; select with dx<4.
__device__ __forceinline__ C8 gather_hash(const uint32_t* __restrict__ t,
                                          const Pt& p) {
    const uint32_t hx = (uint32_t)p.ix;
    const uint32_t dx = hx ^ (hx + 1u);
    const uint32_t y0 = (uint32_t)p.iy * PRIME1, y1 = y0 + PRIME1;
    const uint32_t z0 = (uint32_t)p.iz * PRIME2, z1 = z0 + PRIME2;
    const uint32_t i00 = (hx ^ y0 ^ z0) & T_MASK;
    const uint32_t i10 = (hx ^ y1 ^ z0) & T_MASK;
    const uint32_t i01 = (hx ^ y0 ^ z1) & T_MASK;
    const uint32_t i11 = (hx ^ y1 ^ z1) & T_MASK;
    const uint4 q00 = *(const uint4*)(t + (i00 & ~3u));
    const uint4 q10 = *(const uint4*)(t + (i10 & ~3u));
    const uint4 q01 = *(const uint4*)(t + (i01 & ~3u));
    const uint4 q11 = *(const uint4*)(t + (i11 & ~3u));
    const uint32_t s1 = t[(i00 ^ dx) & T_MASK];
    const uint32_t s3 = t[(i10 ^ dx) & T_MASK];
    const uint32_t s5 = t[(i01 ^ dx) & T_MASK];
    const uint32_t s7 = t[(i11 ^ dx) & T_MASK];
    const bool in4 = (dx < 4u);
    C8 r;
    r.c0 = sel4(q00, i00 & 3u);
    r.c2 = sel4(q10, i10 & 3u);
    r.c4 = sel4(q01, i01 & 3u);
    r.c6 = sel4(q11, i11 & 3u);
    r.c1 = in4 ? sel4(q00, (i00 ^ dx) & 3u) : s1;
    r.c3 = in4 ? sel4(q10, (i10 ^ dx) & 3u) : s3;
    r.c5 = in4 ? sel4(q01, (i01 ^ dx) & 3u) : s5;
    r.c7 = in4 ? sel4(q11, (i11 ^ dx) & 3u) : s7;
    return r;
}

// cell gather (levels 0..4): all 8 corners contiguous, 2 dwordx4 req
__device__ __forceinline__ C8 gather_cell(const uint32_t* __restrict__ t,
                                          int C, const Pt& p) {
    const uint32_t* cb = t + (size_t)((p.iz * C + p.iy) * C + p.ix) * 8;
    const uint4 q0 = *(const uint4*)cb;
    const uint4 q1 = *(const uint4*)(cb + 4);
    C8 r;
    r.c0 = q0.x; r.c1 = q0.y; r.c2 = q0.z; r.c3 = q0.w;
    r.c4 = q1.x; r.c5 = q1.y; r.c6 = q1.z; r.c7 = q1.w;
    return r;
}

__device__ __forceinline__ float2 blend8(const C8& c, const Pt& p) {
    const float wx0 = 1.0f - p.fx, wx1 = p.fx;
    const float wy0 = 1.0f - p.fy, wy1 = p.fy;
    const float wz0 = 1.0f - p.fz, wz1 = p.fz;
    float w, f0 = 0.0f, f1 = 0.0f;
    w = wx0 * wy0 * wz0; f0 = fmaf(w, bf_lo(c.c0), f0); f1 = fmaf(w, bf_hi(c.c0), f1);
    w = wx1 * wy0 * wz0; f0 = fmaf(w, bf_lo(c.c1), f0); f1 = fmaf(w, bf_hi(c.c1), f1);
    w = wx0 * wy1 * wz0; f0 = fmaf(w, bf_lo(c.c2), f0); f1 = fmaf(w, bf_hi(c.c2), f1);
    w = wx1 * wy1 * wz0; f0 = fmaf(w, bf_lo(c.c3), f0); f1 = fmaf(w, bf_hi(c.c3), f1);
    w = wx0 * wy0 * wz1; f0 = fmaf(w, bf_lo(c.c4), f0); f1 = fmaf(w, bf_hi(c.c4), f1);
    w = wx1 * wy0 * wz1; f0 = fmaf(w, bf_lo(c.c5), f0); f1 = fmaf(w, bf_hi(c.c5), f1);
    w = wx0 * wy1 * wz1; f0 = fmaf(w, bf_lo(c.c6), f0); f1 = fmaf(w, bf_hi(c.c6), f1);
    w = wx1 * wy1 * wz1; f0 = fmaf(w, bf_lo(c.c7), f0); f1 = fmaf(w, bf_hi(c.c7), f1);
    float2 o; o.x = f0; o.y = f1;
    return o;
}

// ---------- phase 1: gather + trilinear blend, level-major output ----------
// Thread = ONE (point, level). Rationale (r5 post-mortem): per-wave gather
// throughput is capped (~0.03 lines/cy/wave, latency-bound); aggregate rate
// = resident_waves x cap. So minimize VGPR/maximize occupancy (light threads,
// r1 mapping: occ 56-64%) AND keep lines/point low (r5 layout: ~67M vs 95M).
// blockIdx%8 == l%8 pins XCD k to {cell(k)+hash(k+8)} or {hash(k),hash(k+8)}
// -> <=4MB per XCD, L2-resident (r4 lesson: overflow -> 3x FETCH, +30% time).
__global__ __launch_bounds__(256) void hg_levels(
    const float* __restrict__ x,
    const uint32_t* __restrict__ tabF,   // [11, T] packed bf16x2 (levels 5..15)
    const uint32_t* __restrict__ tabD,   // cell tables (levels 0..4)
    float2* __restrict__ feat,           // [16, N]
    int N, Params P)
{
    const int l = blockIdx.x & 15;
    const int n = (blockIdx.x >> 4) * 256 + threadIdx.x;
    if (n >= N) return;

    const int rl = P.res[l];
    const float rf = (float)(rl - 1);
    const Pt p = mk_pt(x[n * 3 + 0], x[n * 3 + 1], x[n * 3 + 2], rl, rf);

    C8 c;
    if (l < N_CELL) {
        c = gather_cell(tabD + P.dOff[l], rl - 1, p);
    } else {
        c = gather_hash(tabF + (size_t)(l - N_CELL) * T_SIZE, p);
    }

    nt_store_f2(blend8(c, p), &feat[(size_t)l * N + n]);
}

// ---------- phase 2: LDS-tiled transpose [16,N] -> [N,16] ----------
// 128 points/block: reads are 1KB contiguous per level row (full-wave float4),
// writes 2KB contiguous.
__global__ __launch_bounds__(256) void hg_transpose(
    const float2* __restrict__ feat, f4v* __restrict__ out, int N)
{
    __shared__ float2 st[N_LEVELS][131];   // pad 131: <=2-way banks both phases
    const int base = blockIdx.x * 128;
    const int t = threadIdx.x;
#pragma unroll
    for (int i = 0; i < 4; ++i) {
        const int idx = i * 256 + t;           // 0..1023
        const int l = idx >> 6, pp = (idx & 63) * 2;
        const int n = base + pp;
        float2 v0 = make_float2(0.f, 0.f), v1 = v0;
        if (n + 1 < N) {
            const f4v q = __builtin_nontemporal_load((const f4v*)&feat[(size_t)l * N + n]);
            v0.x = q.x; v0.y = q.y; v1.x = q.z; v1.y = q.w;
        } else if (n < N) {
            v0 = nt_load_f2(&feat[(size_t)l * N + n]);
        }
        st[l][pp] = v0; st[l][pp + 1] = v1;
    }
    __syncthreads();
#pragma unroll
    for (int i = 0; i < 4; ++i) {
        const int idx = i * 256 + t;           // 0..1023
        const int p = idx >> 3, k = idx & 7;
        const int n = base + p;
        if (n < N) {
            const float2 a = st[2 * k][p], b = st[2 * k + 1][p];
            f4v o; o.x = a.x; o.y = a.y; o.z = b.x; o.w = b.y;
            __builtin_nontemporal_store(o, &out[(size_t)n * 8 + k]);
        }
    }
}

// ---------- fallback: used only if ws is too small ----------
__global__ __launch_bounds__(256) void hg_fallback(
    const float* __restrict__ x, const float* __restrict__ emb,
    float* __restrict__ out, int N, Params P)
{
    const int gid = blockIdx.x * 256 + threadIdx.x;
    const int n = gid >> 4, l = gid & 15;
    if (n >= N) return;
    const int rl = P.res[l];
    const float rf = (float)(rl - 1);
    float sx = x[n * 3 + 0] * rf, sy = x[n * 3 + 1] * rf, sz = x[n * 3 + 2] * rf;
    int ix = (int)sx; ix = ix < 0 ? 0 : (ix > rl - 2 ? rl - 2 : ix);
    int iy = (int)sy; iy = iy < 0 ? 0 : (iy > rl - 2 ? rl - 2 : iy);
    int iz = (int)sz; iz = iz < 0 ? 0 : (iz > rl - 2 ? rl - 2 : iz);
    const float fx = sx - ix, fy = sy - iy, fz = sz - iz;
    const uint32_t hx0 = (uint32_t)ix, hx1 = hx0 + 1u;
    const uint32_t hy0 = (uint32_t)iy * PRIME1, hy1 = hy0 + PRIME1;
    const uint32_t hz0 = (uint32_t)iz * PRIME2, hz1 = hz0 + PRIME2;
    const float2* tab = (const float2*)emb + (size_t)l * T_SIZE;
    float2 e0 = tab[(hx0 ^ hy0 ^ hz0) & T_MASK], e1 = tab[(hx1 ^ hy0 ^ hz0) & T_MASK];
    float2 e2 = tab[(hx0 ^ hy1 ^ hz0) & T_MASK], e3 = tab[(hx1 ^ hy1 ^ hz0) & T_MASK];
    float2 e4 = tab[(hx0 ^ hy0 ^ hz1) & T_MASK], e5 = tab[(hx1 ^ hy0 ^ hz1) & T_MASK];
    float2 e6 = tab[(hx0 ^ hy1 ^ hz1) & T_MASK], e7 = tab[(hx1 ^ hy1 ^ hz1) & T_MASK];
    const float wx0 = 1.0f - fx, wx1 = fx, wy0 = 1.0f - fy, wy1 = fy, wz0 = 1.0f - fz, wz1 = fz;
    float w, f0 = 0.0f, f1 = 0.0f;
    w = wx0 * wy0 * wz0; f0 = fmaf(w, e0.x, f0); f1 = fmaf(w, e0.y, f1);
    w = wx1 * wy0 * wz0; f0 = fmaf(w, e1.x, f0); f1 = fmaf(w, e1.y, f1);
    w = wx0 * wy1 * wz0; f0 = fmaf(w, e2.x, f0); f1 = fmaf(w, e2.y, f1);
    w = wx1 * wy1 * wz0; f0 = fmaf(w, e3.x, f0); f1 = fmaf(w, e3.y, f1);
    w = wx0 * wy0 * wz1; f0 = fmaf(w, e4.x, f0); f1 = fmaf(w, e4.y, f1);
    w = wx1 * wy0 * wz1; f0 = fmaf(w, e5.x, f0); f1 = fmaf(w, e5.y, f1);
    w = wx0 * wy1 * wz1; f0 = fmaf(w, e6.x, f0); f1 = fmaf(w, e6.y, f1);
    w = wx1 * wy1 * wz1; f0 = fmaf(w, e7.x, f0); f1 = fmaf(w, e7.y, f1);
    float2 o; o.x = f0; o.y = f1;
    ((float2*)out)[(size_t)n * N_LEVELS + l] = o;
}

extern "C" void kernel_launch(void* const* d_in, const int* in_sizes, int n_in,
                              void* d_out, int out_size, void* d_ws, size_t ws_size,
                              hipStream_t stream) {
    const float* x   = (const float*)d_in[0];
    const float* emb = (const float*)d_in[1];
    const int N = in_sizes[0] / 3;

    // CPython-identical level resolutions (truncation-sensitive: 16*b^3 == 32)
    Params P;
    const double b = exp((log(512.0) - log(16.0)) / 15.0);
    for (int i = 0; i < N_LEVELS; ++i)
        P.res[i] = (int)(16.0 * pow(b, (double)i));

    // cell tables (levels 0..4)
    P.cellOffC[0] = 0;
    for (int l = 0; l < N_CELL; ++l) {
        const int C = P.res[l] - 1;
        P.cellOffC[l + 1] = P.cellOffC[l] + C * C * C;
    }
    P.cellTot = P.cellOffC[N_CELL];
    for (int l = 0; l < N_CELL; ++l) P.dOff[l] = P.cellOffC[l] * 8;

    const size_t fine_bytes  = (size_t)N_HASH * T_SIZE * sizeof(uint32_t);        // 22 MB
    const size_t dense_bytes = ((size_t)P.cellTot * 8 * sizeof(uint32_t) + 255) & ~255ull; // ~3.7 MB
    const size_t feat_bytes  = (size_t)N_LEVELS * N * sizeof(float2);             // 128 MB

    if (ws_size >= fine_bytes + dense_bytes + feat_bytes) {
        uint32_t* tabF = (uint32_t*)d_ws;
        uint32_t* tabD = (uint32_t*)((char*)d_ws + fine_bytes);
        float2*   feat = (float2*)((char*)d_ws + fine_bytes + dense_bytes);

        hipLaunchKernelGGL(hg_build_fine, dim3(N_HASH * T_SIZE / 256), dim3(256), 0, stream,
                           (const float2*)emb, tabF);
        hipLaunchKernelGGL(hg_build_cell, dim3((P.cellTot * 8 + 255) / 256), dim3(256), 0, stream,
                           (const float2*)emb, tabD, P);

        const int chunks = (N + 255) / 256;    // 256 points per block, 16 level-blocks
        hipLaunchKernelGGL(hg_levels, dim3(chunks * 16), dim3(256), 0, stream,
                           x, tabF, tabD, feat, N, P);

        hipLaunchKernelGGL(hg_transpose, dim3((N + 127) / 128), dim3(256), 0, stream,
                           feat, (f4v*)d_out, N);
    } else {
        hipLaunchKernelGGL(hg_fallback, dim3((N * 16 + 255) / 256), dim3(256), 0, stream,
                           x, emb, (float*)d_out, N, P);
    }
}

// Round 7
// 542.425 us; speedup vs baseline: 1.3558x; 1.3558x over previous
//
#include <hip/hip_runtime.h>
#include <math.h>
#include <stdint.h>

#define LOG2_T 19
#define T_SIZE (1u << LOG2_T)
#define T_MASK (T_SIZE - 1u)
#define N_LEVELS 16
#define N_CELL 5             // levels 0..4: cell tables (8 corners / 32B entry)
#define N_HASH 11            // levels 5..15: packed bf16 hash tables in tabF
#define PRIME1 2654435761u
#define PRIME2 805459861u

typedef unsigned long long u64;
typedef float f4v __attribute__((ext_vector_type(4)));

struct Params {
    int res[N_LEVELS];
    int dOff[N_CELL];        // dword offset of each cell-table level in tabD
    int cellOffC[N_CELL + 1];// cumulative cell counts (levels 0..4)
    int cellTot;
};

__device__ __forceinline__ float bf_lo(uint32_t v) { return __uint_as_float(v << 16); }
__device__ __forceinline__ float bf_hi(uint32_t v) { return __uint_as_float(v & 0xFFFF0000u); }

__device__ __forceinline__ uint32_t f32_to_bf16_rne(float f) {
    uint32_t u = __float_as_uint(f);
    u += 0x7FFFu + ((u >> 16) & 1u);
    return u >> 16;
}
__device__ __forceinline__ uint32_t pack2(float2 e) {
    return f32_to_bf16_rne(e.x) | (f32_to_bf16_rne(e.y) << 16);
}

__device__ __forceinline__ float2 nt_load_f2(const float2* p) {
    union { float2 f; u64 u; } cv;
    cv.u = __builtin_nontemporal_load((const u64*)p);
    return cv.f;
}
__device__ __forceinline__ void nt_store_f2(float2 v, float2* p) {
    union { float2 f; u64 u; } cv; cv.f = v;
    __builtin_nontemporal_store(cv.u, (u64*)p);
}

// select one dword of a quad by 2-bit index (pure VALU, no dynamic indexing)
__device__ __forceinline__ uint32_t sel4(uint4 q, uint32_t s) {
    const uint32_t a = (s & 1u) ? q.y : q.x;
    const uint32_t b = (s & 1u) ? q.w : q.z;
    return (s & 2u) ? b : a;
}

// ---------- build: hash tables (levels 5..15) fp32 -> packed bf16 ----------
__global__ __launch_bounds__(256) void hg_build_fine(
    const float2* __restrict__ emb, uint32_t* __restrict__ tabF)
{
    const int i = blockIdx.x * 256 + threadIdx.x;          // [0, N_HASH*T)
    tabF[i] = pack2(emb[(size_t)N_CELL * T_SIZE + i]);
}

// ---------- build: cell tables (levels 0..4): 8 corners per cell, 32B ----------
__global__ __launch_bounds__(256) void hg_build_cell(
    const float2* __restrict__ emb, uint32_t* __restrict__ tabD, Params P)
{
    const int i = blockIdx.x * 256 + threadIdx.x;          // one thread per dword
    if (i >= P.cellTot * 8) return;
    const int cg = i >> 3, k = i & 7;                      // cell, corner
    int l = 0;
    while (l < N_CELL - 1 && cg >= P.cellOffC[l + 1]) ++l;
    const int e = cg - P.cellOffC[l];
    const int C = P.res[l] - 1;
    const int ix = e % C; const int r = e / C; const int iy = r % C; const int iz = r / C;
    const uint32_t xx = (uint32_t)(ix + (k & 1));
    const uint32_t yy = (uint32_t)(iy + ((k >> 1) & 1));
    const uint32_t zz = (uint32_t)(iz + (k >> 2));
    const uint32_t h = (xx ^ (yy * PRIME1) ^ (zz * PRIME2)) & T_MASK;
    tabD[P.dOff[l] + e * 8 + k] = pack2(emb[(size_t)l * T_SIZE + h]);
}

// ---------- gather helpers ----------
struct Pt { int ix, iy, iz; float fx, fy, fz; };

__device__ __forceinline__ Pt mk_pt(float x0, float x1, float x2,
                                    int rl, float rf) {
    Pt p;
    const float sx = x0 * rf, sy = x1 * rf, sz = x2 * rf;
    int ix = (int)sx; ix = ix < 0 ? 0 : (ix > rl - 2 ? rl - 2 : ix);
    int iy = (int)sy; iy = iy < 0 ? 0 : (iy > rl - 2 ? rl - 2 : iy);
    int iz = (int)sz; iz = iz < 0 ? 0 : (iz > rl - 2 ? rl - 2 : iz);
    p.ix = ix; p.iy = iy; p.iz = iz;
    p.fx = sx - (float)ix; p.fy = sy - (float)iy; p.fz = sz - (float)iz;
    return p;
}

__device__ __forceinline__ float2 blend8s(
    uint32_t c0, uint32_t c1, uint32_t c2, uint32_t c3,
    uint32_t c4, uint32_t c5, uint32_t c6, uint32_t c7,
    float fx, float fy, float fz)
{
    const float wx0 = 1.0f - fx, wx1 = fx;
    const float wy0 = 1.0f - fy, wy1 = fy;
    const float wz0 = 1.0f - fz, wz1 = fz;
    float w, f0 = 0.0f, f1 = 0.0f;
    w = wx0 * wy0 * wz0; f0 = fmaf(w, bf_lo(c0), f0); f1 = fmaf(w, bf_hi(c0), f1);
    w = wx1 * wy0 * wz0; f0 = fmaf(w, bf_lo(c1), f0); f1 = fmaf(w, bf_hi(c1), f1);
    w = wx0 * wy1 * wz0; f0 = fmaf(w, bf_lo(c2), f0); f1 = fmaf(w, bf_hi(c2), f1);
    w = wx1 * wy1 * wz0; f0 = fmaf(w, bf_lo(c3), f0); f1 = fmaf(w, bf_hi(c3), f1);
    w = wx0 * wy0 * wz1; f0 = fmaf(w, bf_lo(c4), f0); f1 = fmaf(w, bf_hi(c4), f1);
    w = wx1 * wy0 * wz1; f0 = fmaf(w, bf_lo(c5), f0); f1 = fmaf(w, bf_hi(c5), f1);
    w = wx0 * wy1 * wz1; f0 = fmaf(w, bf_lo(c6), f0); f1 = fmaf(w, bf_hi(c6), f1);
    w = wx1 * wy1 * wz1; f0 = fmaf(w, bf_lo(c7), f0); f1 = fmaf(w, bf_hi(c7), f1);
    float2 o; o.x = f0; o.y = f1;
    return o;
}

// ---------- phase 1: gather + trilinear blend, level-major output ----------
// Supply/demand model from r1-r6: random-line L2 supply ceiling ~128 lines/cy
// chip-wide (r1/r2 measured 120-124); time = lines/128 IF demand keeps the
// pipe full. r5/r6 cut lines to ~65M but fell to 53-69 lines/cy because the
// compiler serialized the quad chain (VGPR 24 = only 1-2 loads in flight).
// Fix: thread = ONE point-level (light, r1 demand shape), ONE gather cluster
// (5-9 loads, 20-36 result VGPRs) pinned before the blend by sched_barrier(0),
// __launch_bounds__(256,6) so the allocator accepts ~50 VGPR. Verification
// signal: VGPR_Count >= 40 (24-28 means the compiler won again).
// blockIdx%8 == l%8 -> XCD k caches {cell(k)+hash(k+8)} or {hash(k),hash(k+8)}
// <= 4MB, L2-resident (r4: overflow -> 3x FETCH, +30% time).
__global__ __launch_bounds__(256, 6) void hg_levels(
    const float* __restrict__ x,
    const uint32_t* __restrict__ tabF,   // [11, T] packed bf16x2 (levels 5..15)
    const uint32_t* __restrict__ tabD,   // cell tables (levels 0..4)
    float2* __restrict__ feat,           // [16, N]
    int N, Params P)
{
    const int l = blockIdx.x & 15;
    const int n = (blockIdx.x >> 4) * 256 + threadIdx.x;
    if (n >= N) return;

    const int rl = P.res[l];
    const float rf = (float)(rl - 1);
    const Pt p = mk_pt(x[n * 3 + 0], x[n * 3 + 1], x[n * 3 + 2], rl, rf);

    float2 o;
    if (l < N_CELL) {
        // ---- cell gather: 2 aligned 16B lines ----
        const uint32_t* __restrict__ t = tabD + P.dOff[l];
        const int C = rl - 1;
        const uint32_t* cb = t + (size_t)((p.iz * C + p.iy) * C + p.ix) * 8;
        const uint4 q0 = *(const uint4*)cb;
        const uint4 q1 = *(const uint4*)(cb + 4);
        __builtin_amdgcn_sched_barrier(0);
        o = blend8s(q0.x, q0.y, q0.z, q0.w, q1.x, q1.y, q1.z, q1.w,
                    p.fx, p.fy, p.fz);
    } else {
        // ---- quad-hash gather: 4 aligned 16B lines + divergent extras ----
        const uint32_t* __restrict__ t = tabF + (size_t)(l - N_CELL) * T_SIZE;
        const uint32_t hx = (uint32_t)p.ix;
        const uint32_t dx = hx ^ (hx + 1u);
        const uint32_t y0 = (uint32_t)p.iy * PRIME1, y1 = y0 + PRIME1;
        const uint32_t z0 = (uint32_t)p.iz * PRIME2, z1 = z0 + PRIME2;
        const uint32_t i00 = (hx ^ y0 ^ z0) & T_MASK;
        const uint32_t i10 = (hx ^ y1 ^ z0) & T_MASK;
        const uint32_t i01 = (hx ^ y0 ^ z1) & T_MASK;
        const uint32_t i11 = (hx ^ y1 ^ z1) & T_MASK;
        const uint4 q00 = *(const uint4*)(t + (i00 & ~3u));
        const uint4 q10 = *(const uint4*)(t + (i10 & ~3u));
        const uint4 q01 = *(const uint4*)(t + (i01 & ~3u));
        const uint4 q11 = *(const uint4*)(t + (i11 & ~3u));
        // divergent second-x-corner loads (25% of lanes: ix%4==3)
        uint32_t s1 = 0, s3 = 0, s5 = 0, s7 = 0;
        const bool in4 = (dx < 4u);
        if (!in4) {
            s1 = t[(i00 ^ dx) & T_MASK];
            s3 = t[(i10 ^ dx) & T_MASK];
            s5 = t[(i01 ^ dx) & T_MASK];
            s7 = t[(i11 ^ dx) & T_MASK];
        }
        __builtin_amdgcn_sched_barrier(0);
        const uint32_t c0 = sel4(q00, i00 & 3u);
        const uint32_t c2 = sel4(q10, i10 & 3u);
        const uint32_t c4 = sel4(q01, i01 & 3u);
        const uint32_t c6 = sel4(q11, i11 & 3u);
        const uint32_t c1 = in4 ? sel4(q00, (i00 ^ dx) & 3u) : s1;
        const uint32_t c3 = in4 ? sel4(q10, (i10 ^ dx) & 3u) : s3;
        const uint32_t c5 = in4 ? sel4(q01, (i01 ^ dx) & 3u) : s5;
        const uint32_t c7 = in4 ? sel4(q11, (i11 ^ dx) & 3u) : s7;
        o = blend8s(c0, c1, c2, c3, c4, c5, c6, c7, p.fx, p.fy, p.fz);
    }

    nt_store_f2(o, &feat[(size_t)l * N + n]);
}

// ---------- phase 2: LDS-tiled transpose [16,N] -> [N,16] ----------
// 128 points/block: reads are 1KB contiguous per level row (full-wave float4),
// writes 2KB contiguous.
__global__ __launch_bounds__(256) void hg_transpose(
    const float2* __restrict__ feat, f4v* __restrict__ out, int N)
{
    __shared__ float2 st[N_LEVELS][131];   // pad 131: <=2-way banks both phases
    const int base = blockIdx.x * 128;
    const int t = threadIdx.x;
#pragma unroll
    for (int i = 0; i < 4; ++i) {
        const int idx = i * 256 + t;           // 0..1023
        const int l = idx >> 6, pp = (idx & 63) * 2;
        const int n = base + pp;
        float2 v0 = make_float2(0.f, 0.f), v1 = v0;
        if (n + 1 < N) {
            const f4v q = __builtin_nontemporal_load((const f4v*)&feat[(size_t)l * N + n]);
            v0.x = q.x; v0.y = q.y; v1.x = q.z; v1.y = q.w;
        } else if (n < N) {
            v0 = nt_load_f2(&feat[(size_t)l * N + n]);
        }
        st[l][pp] = v0; st[l][pp + 1] = v1;
    }
    __syncthreads();
#pragma unroll
    for (int i = 0; i < 4; ++i) {
        const int idx = i * 256 + t;           // 0..1023
        const int p = idx >> 3, k = idx & 7;
        const int n = base + p;
        if (n < N) {
            const float2 a = st[2 * k][p], b = st[2 * k + 1][p];
            f4v o; o.x = a.x; o.y = a.y; o.z = b.x; o.w = b.y;
            __builtin_nontemporal_store(o, &out[(size_t)n * 8 + k]);
        }
    }
}

// ---------- fallback: used only if ws is too small ----------
__global__ __launch_bounds__(256) void hg_fallback(
    const float* __restrict__ x, const float* __restrict__ emb,
    float* __restrict__ out, int N, Params P)
{
    const int gid = blockIdx.x * 256 + threadIdx.x;
    const int n = gid >> 4, l = gid & 15;
    if (n >= N) return;
    const int rl = P.res[l];
    const float rf = (float)(rl - 1);
    float sx = x[n * 3 + 0] * rf, sy = x[n * 3 + 1] * rf, sz = x[n * 3 + 2] * rf;
    int ix = (int)sx; ix = ix < 0 ? 0 : (ix > rl - 2 ? rl - 2 : ix);
    int iy = (int)sy; iy = iy < 0 ? 0 : (iy > rl - 2 ? rl - 2 : iy);
    int iz = (int)sz; iz = iz < 0 ? 0 : (iz > rl - 2 ? rl - 2 : iz);
    const float fx = sx - ix, fy = sy - iy, fz = sz - iz;
    const uint32_t hx0 = (uint32_t)ix, hx1 = hx0 + 1u;
    const uint32_t hy0 = (uint32_t)iy * PRIME1, hy1 = hy0 + PRIME1;
    const uint32_t hz0 = (uint32_t)iz * PRIME2, hz1 = hz0 + PRIME2;
    const float2* tab = (const float2*)emb + (size_t)l * T_SIZE;
    float2 e0 = tab[(hx0 ^ hy0 ^ hz0) & T_MASK], e1 = tab[(hx1 ^ hy0 ^ hz0) & T_MASK];
    float2 e2 = tab[(hx0 ^ hy1 ^ hz0) & T_MASK], e3 = tab[(hx1 ^ hy1 ^ hz0) & T_MASK];
    float2 e4 = tab[(hx0 ^ hy0 ^ hz1) & T_MASK], e5 = tab[(hx1 ^ hy0 ^ hz1) & T_MASK];
    float2 e6 = tab[(hx0 ^ hy1 ^ hz1) & T_MASK], e7 = tab[(hx1 ^ hy1 ^ hz1) & T_MASK];
    const float wx0 = 1.0f - fx, wx1 = fx, wy0 = 1.0f - fy, wy1 = fy, wz0 = 1.0f - fz, wz1 = fz;
    float w, f0 = 0.0f, f1 = 0.0f;
    w = wx0 * wy0 * wz0; f0 = fmaf(w, e0.x, f0); f1 = fmaf(w, e0.y, f1);
    w = wx1 * wy0 * wz0; f0 = fmaf(w, e1.x, f0); f1 = fmaf(w, e1.y, f1);
    w = wx0 * wy1 * wz0; f0 = fmaf(w, e2.x, f0); f1 = fmaf(w, e2.y, f1);
    w = wx1 * wy1 * wz0; f0 = fmaf(w, e3.x, f0); f1 = fmaf(w, e3.y, f1);
    w = wx0 * wy0 * wz1; f0 = fmaf(w, e4.x, f0); f1 = fmaf(w, e4.y, f1);
    w = wx1 * wy0 * wz1; f0 = fmaf(w, e5.x, f0); f1 = fmaf(w, e5.y, f1);
    w = wx0 * wy1 * wz1; f0 = fmaf(w, e6.x, f0); f1 = fmaf(w, e6.y, f1);
    w = wx1 * wy1 * wz1; f0 = fmaf(w, e7.x, f0); f1 = fmaf(w, e7.y, f1);
    float2 o; o.x = f0; o.y = f1;
    ((float2*)out)[(size_t)n * N_LEVELS + l] = o;
}

extern "C" void kernel_launch(void* const* d_in, const int* in_sizes, int n_in,
                              void* d_out, int out_size, void* d_ws, size_t ws_size,
                              hipStream_t stream) {
    const float* x   = (const float*)d_in[0];
    const float* emb = (const float*)d_in[1];
    const int N = in_sizes[0] / 3;

    // CPython-identical level resolutions (truncation-sensitive: 16*b^3 == 32)
    Params P;
    const double b = exp((log(512.0) - log(16.0)) / 15.0);
    for (int i = 0; i < N_LEVELS; ++i)
        P.res[i] = (int)(16.0 * pow(b, (double)i));

    // cell tables (levels 0..4)
    P.cellOffC[0] = 0;
    for (int l = 0; l < N_CELL; ++l) {
        const int C = P.res[l] - 1;
        P.cellOffC[l + 1] = P.cellOffC[l] + C * C * C;
    }
    P.cellTot = P.cellOffC[N_CELL];
    for (int l = 0; l < N_CELL; ++l) P.dOff[l] = P.cellOffC[l] * 8;

    const size_t fine_bytes  = (size_t)N_HASH * T_SIZE * sizeof(uint32_t);        // 22 MB
    const size_t dense_bytes = ((size_t)P.cellTot * 8 * sizeof(uint32_t) + 255) & ~255ull; // ~3.7 MB
    const size_t feat_bytes  = (size_t)N_LEVELS * N * sizeof(float2);             // 128 MB

    if (ws_size >= fine_bytes + dense_bytes + feat_bytes) {
        uint32_t* tabF = (uint32_t*)d_ws;
        uint32_t* tabD = (uint32_t*)((char*)d_ws + fine_bytes);
        float2*   feat = (float2*)((char*)d_ws + fine_bytes + dense_bytes);

        hipLaunchKernelGGL(hg_build_fine, dim3(N_HASH * T_SIZE / 256), dim3(256), 0, stream,
                           (const float2*)emb, tabF);
        hipLaunchKernelGGL(hg_build_cell, dim3((P.cellTot * 8 + 255) / 256), dim3(256), 0, stream,
                           (const float2*)emb, tabD, P);

        const int chunks = (N + 255) / 256;    // 256 points per block, 16 level-blocks
        hipLaunchKernelGGL(hg_levels, dim3(chunks * 16), dim3(256), 0, stream,
                           x, tabF, tabD, feat, N, P);

        hipLaunchKernelGGL(hg_transpose, dim3((N + 127) / 128), dim3(256), 0, stream,
                           feat, (f4v*)d_out, N);
    } else {
        hipLaunchKernelGGL(hg_fallback, dim3((N * 16 + 255) / 256), dim3(256), 0, stream,
                           x, emb, (float*)d_out, N, P);
    }
}

// Round 8
// 509.203 us; speedup vs baseline: 1.4442x; 1.0652x over previous
//
#include <hip/hip_runtime.h>
#include <math.h>
#include <stdint.h>

#define LOG2_T 19
#define T_SIZE (1u << LOG2_T)
#define T_MASK (T_SIZE - 1u)
#define N_LEVELS 16
#define N_CELL 5             // levels 0..4: cell tables (8 corners / 32B entry)
#define N_HASH 11            // levels 5..15: packed bf16 hash tables in tabF
#define PRIME1 2654435761u
#define PRIME2 805459861u

typedef unsigned long long u64;
typedef float f4v __attribute__((ext_vector_type(4)));

struct Params {
    int res[N_LEVELS];
    int dOff[N_CELL];        // dword offset of each cell-table level in tabD
    int cellOffC[N_CELL + 1];// cumulative cell counts (levels 0..4)
    int cellTot;
    int chunks;              // (N+255)/256
    int don;                 // donated chunks per donor level (L13,L14,L15)
};

__device__ __forceinline__ float bf_lo(uint32_t v) { return __uint_as_float(v << 16); }
__device__ __forceinline__ float bf_hi(uint32_t v) { return __uint_as_float(v & 0xFFFF0000u); }

__device__ __forceinline__ uint32_t f32_to_bf16_rne(float f) {
    uint32_t u = __float_as_uint(f);
    u += 0x7FFFu + ((u >> 16) & 1u);
    return u >> 16;
}
__device__ __forceinline__ uint32_t pack2(float2 e) {
    return f32_to_bf16_rne(e.x) | (f32_to_bf16_rne(e.y) << 16);
}

__device__ __forceinline__ void nt_store_f2(float2 v, float2* p) {
    union { float2 f; u64 u; } cv; cv.f = v;
    __builtin_nontemporal_store(cv.u, (u64*)p);
}

// select one dword of a quad by 2-bit index (pure VALU, no dynamic indexing)
__device__ __forceinline__ uint32_t sel4(uint4 q, uint32_t s) {
    const uint32_t a = (s & 1u) ? q.y : q.x;
    const uint32_t b = (s & 1u) ? q.w : q.z;
    return (s & 2u) ? b : a;
}

// ---------- build: hash tables (levels 5..15) fp32 -> packed bf16 ----------
__global__ __launch_bounds__(256) void hg_build_fine(
    const float2* __restrict__ emb, uint32_t* __restrict__ tabF)
{
    const int i = blockIdx.x * 256 + threadIdx.x;          // [0, N_HASH*T)
    tabF[i] = pack2(emb[(size_t)N_CELL * T_SIZE + i]);
}

// ---------- build: cell tables (levels 0..4): 8 corners per cell, 32B ----------
__global__ __launch_bounds__(256) void hg_build_cell(
    const float2* __restrict__ emb, uint32_t* __restrict__ tabD, Params P)
{
    const int i = blockIdx.x * 256 + threadIdx.x;          // one thread per dword
    if (i >= P.cellTot * 8) return;
    const int cg = i >> 3, k = i & 7;                      // cell, corner
    int l = 0;
    while (l < N_CELL - 1 && cg >= P.cellOffC[l + 1]) ++l;
    const int e = cg - P.cellOffC[l];
    const int C = P.res[l] - 1;
    const int ix = e % C; const int r = e / C; const int iy = r % C; const int iz = r / C;
    const uint32_t xx = (uint32_t)(ix + (k & 1));
    const uint32_t yy = (uint32_t)(iy + ((k >> 1) & 1));
    const uint32_t zz = (uint32_t)(iz + (k >> 2));
    const uint32_t h = (xx ^ (yy * PRIME1) ^ (zz * PRIME2)) & T_MASK;
    tabD[P.dOff[l] + e * 8 + k] = pack2(emb[(size_t)l * T_SIZE + h]);
}

// ---------- gather helpers ----------
struct Pt { int ix, iy, iz; float fx, fy, fz; };

__device__ __forceinline__ Pt mk_pt(float x0, float x1, float x2,
                                    int rl, float rf) {
    Pt p;
    const float sx = x0 * rf, sy = x1 * rf, sz = x2 * rf;
    int ix = (int)sx; ix = ix < 0 ? 0 : (ix > rl - 2 ? rl - 2 : ix);
    int iy = (int)sy; iy = iy < 0 ? 0 : (iy > rl - 2 ? rl - 2 : iy);
    int iz = (int)sz; iz = iz < 0 ? 0 : (iz > rl - 2 ? rl - 2 : iz);
    p.ix = ix; p.iy = iy; p.iz = iz;
    p.fx = sx - (float)ix; p.fy = sy - (float)iy; p.fz = sz - (float)iz;
    return p;
}

__device__ __forceinline__ float2 blend8s(
    uint32_t c0, uint32_t c1, uint32_t c2, uint32_t c3,
    uint32_t c4, uint32_t c5, uint32_t c6, uint32_t c7,
    float fx, float fy, float fz)
{
    const float wx0 = 1.0f - fx, wx1 = fx;
    const float wy0 = 1.0f - fy, wy1 = fy;
    const float wz0 = 1.0f - fz, wz1 = fz;
    float w, f0 = 0.0f, f1 = 0.0f;
    w = wx0 * wy0 * wz0; f0 = fmaf(w, bf_lo(c0), f0); f1 = fmaf(w, bf_hi(c0), f1);
    w = wx1 * wy0 * wz0; f0 = fmaf(w, bf_lo(c1), f0); f1 = fmaf(w, bf_hi(c1), f1);
    w = wx0 * wy1 * wz0; f0 = fmaf(w, bf_lo(c2), f0); f1 = fmaf(w, bf_hi(c2), f1);
    w = wx1 * wy1 * wz0; f0 = fmaf(w, bf_lo(c3), f0); f1 = fmaf(w, bf_hi(c3), f1);
    w = wx0 * wy0 * wz1; f0 = fmaf(w, bf_lo(c4), f0); f1 = fmaf(w, bf_hi(c4), f1);
    w = wx1 * wy0 * wz1; f0 = fmaf(w, bf_lo(c5), f0); f1 = fmaf(w, bf_hi(c5), f1);
    w = wx0 * wy1 * wz1; f0 = fmaf(w, bf_lo(c6), f0); f1 = fmaf(w, bf_hi(c6), f1);
    w = wx1 * wy1 * wz1; f0 = fmaf(w, bf_lo(c7), f0); f1 = fmaf(w, bf_hi(c7), f1);
    float2 o; o.x = f0; o.y = f1;
    return o;
}

// ---------- phase 1: gather + trilinear blend, level-major output ----------
// Gather structure identical to r7 (345us). New: XCD LOAD REBALANCE.
// r7 evidence: pairs {k,k+8} cost 7 lines/pt on XCDs 0-4 (cell+hash) vs 10 on
// XCDs 5-7 (hash+hash); chip ran 84 lines/cy vs the ~120-128 supply ceiling
// measured in r1/r2 -> straggler-bound on XCDs 5-7. Fix: XCDs 5/6/7 donate the
// LAST `don` chunks of levels 13/14/15 to XCDs 0/1/2. Per-XCD cost becomes
// (8.5,8.5,8.5,7,7,8.5,8.5,8.5); receiver L2 footprint 4.11-4.42MB (<=10% over
// 4MB, mild thrash accepted). Work mapping: xcd = blockIdx&7, w = blockIdx>>3.
__global__ __launch_bounds__(256, 6) void hg_levels(
    const float* __restrict__ x,
    const uint32_t* __restrict__ tabF,   // [11, T] packed bf16x2 (levels 5..15)
    const uint32_t* __restrict__ tabD,   // cell tables (levels 0..4)
    float2* __restrict__ feat,           // [16, N]
    int N, Params P)
{
    const int xcd = blockIdx.x & 7;
    const int w   = blockIdx.x >> 3;
    const int ch  = P.chunks, D = P.don;

    int l, chunk;
    if (w < ch) { l = xcd; chunk = w; }
    else if (xcd < 3) {
        if (w < 2 * ch) { l = xcd + 8; chunk = w - ch; }
        else            { l = 13 + xcd; chunk = (ch - D) + (w - 2 * ch); } // donated tail
    } else if (xcd < 5) {
        if (w < 2 * ch) { l = xcd + 8; chunk = w - ch; } else return;
    } else {
        if (w < 2 * ch - D) { l = xcd + 8; chunk = w - ch; } else return;  // keeps first ch-D
    }

    const int n = chunk * 256 + threadIdx.x;
    if (n >= N) return;

    const int rl = P.res[l];
    const float rf = (float)(rl - 1);
    const Pt p = mk_pt(x[n * 3 + 0], x[n * 3 + 1], x[n * 3 + 2], rl, rf);

    float2 o;
    if (l < N_CELL) {
        // ---- cell gather: 2 aligned 16B lines ----
        const uint32_t* __restrict__ t = tabD + P.dOff[l];
        const int C = rl - 1;
        const uint32_t* cb = t + (size_t)((p.iz * C + p.iy) * C + p.ix) * 8;
        const uint4 q0 = *(const uint4*)cb;
        const uint4 q1 = *(const uint4*)(cb + 4);
        __builtin_amdgcn_sched_barrier(0);
        o = blend8s(q0.x, q0.y, q0.z, q0.w, q1.x, q1.y, q1.z, q1.w,
                    p.fx, p.fy, p.fz);
    } else {
        // ---- quad-hash gather: 4 aligned 16B lines + divergent extras ----
        const uint32_t* __restrict__ t = tabF + (size_t)(l - N_CELL) * T_SIZE;
        const uint32_t hx = (uint32_t)p.ix;
        const uint32_t dx = hx ^ (hx + 1u);
        const uint32_t y0 = (uint32_t)p.iy * PRIME1, y1 = y0 + PRIME1;
        const uint32_t z0 = (uint32_t)p.iz * PRIME2, z1 = z0 + PRIME2;
        const uint32_t i00 = (hx ^ y0 ^ z0) & T_MASK;
        const uint32_t i10 = (hx ^ y1 ^ z0) & T_MASK;
        const uint32_t i01 = (hx ^ y0 ^ z1) & T_MASK;
        const uint32_t i11 = (hx ^ y1 ^ z1) & T_MASK;
        const uint4 q00 = *(const uint4*)(t + (i00 & ~3u));
        const uint4 q10 = *(const uint4*)(t + (i10 & ~3u));
        const uint4 q01 = *(const uint4*)(t + (i01 & ~3u));
        const uint4 q11 = *(const uint4*)(t + (i11 & ~3u));
        // divergent second-x-corner loads (25% of lanes: ix%4==3)
        uint32_t s1 = 0, s3 = 0, s5 = 0, s7 = 0;
        const bool in4 = (dx < 4u);
        if (!in4) {
            s1 = t[(i00 ^ dx) & T_MASK];
            s3 = t[(i10 ^ dx) & T_MASK];
            s5 = t[(i01 ^ dx) & T_MASK];
            s7 = t[(i11 ^ dx) & T_MASK];
        }
        __builtin_amdgcn_sched_barrier(0);
        const uint32_t c0 = sel4(q00, i00 & 3u);
        const uint32_t c2 = sel4(q10, i10 & 3u);
        const uint32_t c4 = sel4(q01, i01 & 3u);
        const uint32_t c6 = sel4(q11, i11 & 3u);
        const uint32_t c1 = in4 ? sel4(q00, (i00 ^ dx) & 3u) : s1;
        const uint32_t c3 = in4 ? sel4(q10, (i10 ^ dx) & 3u) : s3;
        const uint32_t c5 = in4 ? sel4(q01, (i01 ^ dx) & 3u) : s5;
        const uint32_t c7 = in4 ? sel4(q11, (i11 ^ dx) & 3u) : s7;
        o = blend8s(c0, c1, c2, c3, c4, c5, c6, c7, p.fx, p.fy, p.fz);
    }

    // NT store: write-once stream, must not evict the pinned L2 tables
    nt_store_f2(o, &feat[(size_t)l * N + n]);
}

// ---------- phase 2: LDS-tiled transpose [16,N] -> [N,16] ----------
// NO nontemporal hints this round (r1-r7: total-minus-levels stuck at ~197us
// across two structurally different transposes; testing the NT hypothesis).
// 128 points/block: 1KB contiguous reads per level row, 2KB contiguous writes.
__global__ __launch_bounds__(256) void hg_transpose(
    const float2* __restrict__ feat, f4v* __restrict__ out, int N)
{
    __shared__ float2 st[N_LEVELS][131];   // pad 131: <=2-way banks both phases
    const int base = blockIdx.x * 128;
    const int t = threadIdx.x;
#pragma unroll
    for (int i = 0; i < 4; ++i) {
        const int idx = i * 256 + t;           // 0..1023
        const int l = idx >> 6, pp = (idx & 63) * 2;
        const int n = base + pp;
        float2 v0 = make_float2(0.f, 0.f), v1 = v0;
        if (n + 1 < N) {
            const f4v q = *(const f4v*)&feat[(size_t)l * N + n];
            v0.x = q.x; v0.y = q.y; v1.x = q.z; v1.y = q.w;
        } else if (n < N) {
            v0 = feat[(size_t)l * N + n];
        }
        st[l][pp] = v0; st[l][pp + 1] = v1;
    }
    __syncthreads();
#pragma unroll
    for (int i = 0; i < 4; ++i) {
        const int idx = i * 256 + t;           // 0..1023
        const int p = idx >> 3, k = idx & 7;
        const int n = base + p;
        if (n < N) {
            const float2 a = st[2 * k][p], b = st[2 * k + 1][p];
            f4v o; o.x = a.x; o.y = a.y; o.z = b.x; o.w = b.y;
            out[(size_t)n * 8 + k] = o;
        }
    }
}

// ---------- fallback: used only if ws is too small ----------
__global__ __launch_bounds__(256) void hg_fallback(
    const float* __restrict__ x, const float* __restrict__ emb,
    float* __restrict__ out, int N, Params P)
{
    const int gid = blockIdx.x * 256 + threadIdx.x;
    const int n = gid >> 4, l = gid & 15;
    if (n >= N) return;
    const int rl = P.res[l];
    const float rf = (float)(rl - 1);
    float sx = x[n * 3 + 0] * rf, sy = x[n * 3 + 1] * rf, sz = x[n * 3 + 2] * rf;
    int ix = (int)sx; ix = ix < 0 ? 0 : (ix > rl - 2 ? rl - 2 : ix);
    int iy = (int)sy; iy = iy < 0 ? 0 : (iy > rl - 2 ? rl - 2 : iy);
    int iz = (int)sz; iz = iz < 0 ? 0 : (iz > rl - 2 ? rl - 2 : iz);
    const float fx = sx - ix, fy = sy - iy, fz = sz - iz;
    const uint32_t hx0 = (uint32_t)ix, hx1 = hx0 + 1u;
    const uint32_t hy0 = (uint32_t)iy * PRIME1, hy1 = hy0 + PRIME1;
    const uint32_t hz0 = (uint32_t)iz * PRIME2, hz1 = hz0 + PRIME2;
    const float2* tab = (const float2*)emb + (size_t)l * T_SIZE;
    float2 e0 = tab[(hx0 ^ hy0 ^ hz0) & T_MASK], e1 = tab[(hx1 ^ hy0 ^ hz0) & T_MASK];
    float2 e2 = tab[(hx0 ^ hy1 ^ hz0) & T_MASK], e3 = tab[(hx1 ^ hy1 ^ hz0) & T_MASK];
    float2 e4 = tab[(hx0 ^ hy0 ^ hz1) & T_MASK], e5 = tab[(hx1 ^ hy0 ^ hz1) & T_MASK];
    float2 e6 = tab[(hx0 ^ hy1 ^ hz1) & T_MASK], e7 = tab[(hx1 ^ hy1 ^ hz1) & T_MASK];
    const float wx0 = 1.0f - fx, wx1 = fx, wy0 = 1.0f - fy, wy1 = fy, wz0 = 1.0f - fz, wz1 = fz;
    float w, f0 = 0.0f, f1 = 0.0f;
    w = wx0 * wy0 * wz0; f0 = fmaf(w, e0.x, f0); f1 = fmaf(w, e0.y, f1);
    w = wx1 * wy0 * wz0; f0 = fmaf(w, e1.x, f0); f1 = fmaf(w, e1.y, f1);
    w = wx0 * wy1 * wz0; f0 = fmaf(w, e2.x, f0); f1 = fmaf(w, e2.y, f1);
    w = wx1 * wy1 * wz0; f0 = fmaf(w, e3.x, f0); f1 = fmaf(w, e3.y, f1);
    w = wx0 * wy0 * wz1; f0 = fmaf(w, e4.x, f0); f1 = fmaf(w, e4.y, f1);
    w = wx1 * wy0 * wz1; f0 = fmaf(w, e5.x, f0); f1 = fmaf(w, e5.y, f1);
    w = wx0 * wy1 * wz1; f0 = fmaf(w, e6.x, f0); f1 = fmaf(w, e6.y, f1);
    w = wx1 * wy1 * wz1; f0 = fmaf(w, e7.x, f0); f1 = fmaf(w, e7.y, f1);
    float2 o; o.x = f0; o.y = f1;
    ((float2*)out)[(size_t)n * N_LEVELS + l] = o;
}

extern "C" void kernel_launch(void* const* d_in, const int* in_sizes, int n_in,
                              void* d_out, int out_size, void* d_ws, size_t ws_size,
                              hipStream_t stream) {
    const float* x   = (const float*)d_in[0];
    const float* emb = (const float*)d_in[1];
    const int N = in_sizes[0] / 3;

    // CPython-identical level resolutions (truncation-sensitive: 16*b^3 == 32)
    Params P;
    const double b = exp((log(512.0) - log(16.0)) / 15.0);
    for (int i = 0; i < N_LEVELS; ++i)
        P.res[i] = (int)(16.0 * pow(b, (double)i));

    // cell tables (levels 0..4)
    P.cellOffC[0] = 0;
    for (int l = 0; l < N_CELL; ++l) {
        const int C = P.res[l] - 1;
        P.cellOffC[l + 1] = P.cellOffC[l] + C * C * C;
    }
    P.cellTot = P.cellOffC[N_CELL];
    for (int l = 0; l < N_CELL; ++l) P.dOff[l] = P.cellOffC[l] * 8;

    P.chunks = (N + 255) / 256;
    P.don    = (P.chunks * 3) / 10;        // balance: 7+5a = 10-5a -> a = 0.3

    const size_t fine_bytes  = (size_t)N_HASH * T_SIZE * sizeof(uint32_t);        // 22 MB
    const size_t dense_bytes = ((size_t)P.cellTot * 8 * sizeof(uint32_t) + 255) & ~255ull; // ~3.7 MB
    const size_t feat_bytes  = (size_t)N_LEVELS * N * sizeof(float2);             // 128 MB

    if (ws_size >= fine_bytes + dense_bytes + feat_bytes) {
        uint32_t* tabF = (uint32_t*)d_ws;
        uint32_t* tabD = (uint32_t*)((char*)d_ws + fine_bytes);
        float2*   feat = (float2*)((char*)d_ws + fine_bytes + dense_bytes);

        hipLaunchKernelGGL(hg_build_fine, dim3(N_HASH * T_SIZE / 256), dim3(256), 0, stream,
                           (const float2*)emb, tabF);
        hipLaunchKernelGGL(hg_build_cell, dim3((P.cellTot * 8 + 255) / 256), dim3(256), 0, stream,
                           (const float2*)emb, tabD, P);

        // grid: 8 XCD slots x (2*chunks + don) work indices; surplus blocks exit
        hipLaunchKernelGGL(hg_levels, dim3(8 * (2 * P.chunks + P.don)), dim3(256), 0, stream,
                           x, tabF, tabD, feat, N, P);

        hipLaunchKernelGGL(hg_transpose, dim3((N + 127) / 128), dim3(256), 0, stream,
                           feat, (f4v*)d_out, N);
    } else {
        hipLaunchKernelGGL(hg_fallback, dim3((N * 16 + 255) / 256), dim3(256), 0, stream,
                           x, emb, (float*)d_out, N, P);
    }
}

// Round 9
// 508.189 us; speedup vs baseline: 1.4471x; 1.0020x over previous
//
#include <hip/hip_runtime.h>
#include <math.h>
#include <stdint.h>

#define LOG2_T 19
#define T_SIZE (1u << LOG2_T)
#define T_MASK (T_SIZE - 1u)
#define N_LEVELS 16
#define N_CELL 5             // levels 0..4: cell tables (8 corners / 32B entry)
#define N_HASH 11            // levels 5..15: packed bf16 hash tables in tabF
#define PRIME1 2654435761u
#define PRIME2 805459861u

typedef unsigned long long u64;
typedef float f4v __attribute__((ext_vector_type(4)));

struct Params {
    int res[N_LEVELS];
    int dOff[N_CELL];        // dword offset of each cell-table level in tabD
    int cellOffC[N_CELL + 1];// cumulative cell counts (levels 0..4)
    int cellTot;
    int chunks;              // (N+255)/256
    int don;                 // donated chunks per donor level (L13,L14,L15)
};

__device__ __forceinline__ float bf_lo(uint32_t v) { return __uint_as_float(v << 16); }
__device__ __forceinline__ float bf_hi(uint32_t v) { return __uint_as_float(v & 0xFFFF0000u); }

__device__ __forceinline__ uint32_t f32_to_bf16_rne(float f) {
    uint32_t u = __float_as_uint(f);
    u += 0x7FFFu + ((u >> 16) & 1u);
    return u >> 16;
}
__device__ __forceinline__ uint32_t pack2(float2 e) {
    return f32_to_bf16_rne(e.x) | (f32_to_bf16_rne(e.y) << 16);
}

__device__ __forceinline__ void nt_store_f2(float2 v, float2* p) {
    union { float2 f; u64 u; } cv; cv.f = v;
    __builtin_nontemporal_store(cv.u, (u64*)p);
}

// select one dword of a quad by 2-bit index (pure VALU, no dynamic indexing)
__device__ __forceinline__ uint32_t sel4(uint4 q, uint32_t s) {
    const uint32_t a = (s & 1u) ? q.y : q.x;
    const uint32_t b = (s & 1u) ? q.w : q.z;
    return (s & 2u) ? b : a;
}

// ---------- build: hash tables (levels 5..15) fp32 -> packed bf16 ----------
__global__ __launch_bounds__(256) void hg_build_fine(
    const float2* __restrict__ emb, uint32_t* __restrict__ tabF)
{
    const int i = blockIdx.x * 256 + threadIdx.x;          // [0, N_HASH*T)
    tabF[i] = pack2(emb[(size_t)N_CELL * T_SIZE + i]);
}

// ---------- build: cell tables (levels 0..4): 8 corners per cell, 32B ----------
__global__ __launch_bounds__(256) void hg_build_cell(
    const float2* __restrict__ emb, uint32_t* __restrict__ tabD, Params P)
{
    const int i = blockIdx.x * 256 + threadIdx.x;          // one thread per dword
    if (i >= P.cellTot * 8) return;
    const int cg = i >> 3, k = i & 7;                      // cell, corner
    int l = 0;
    while (l < N_CELL - 1 && cg >= P.cellOffC[l + 1]) ++l;
    const int e = cg - P.cellOffC[l];
    const int C = P.res[l] - 1;
    const int ix = e % C; const int r = e / C; const int iy = r % C; const int iz = r / C;
    const uint32_t xx = (uint32_t)(ix + (k & 1));
    const uint32_t yy = (uint32_t)(iy + ((k >> 1) & 1));
    const uint32_t zz = (uint32_t)(iz + (k >> 2));
    const uint32_t h = (xx ^ (yy * PRIME1) ^ (zz * PRIME2)) & T_MASK;
    tabD[P.dOff[l] + e * 8 + k] = pack2(emb[(size_t)l * T_SIZE + h]);
}

// ---------- gather helpers ----------
struct Pt { int ix, iy, iz; float fx, fy, fz; };

__device__ __forceinline__ Pt mk_pt(float x0, float x1, float x2,
                                    int rl, float rf) {
    Pt p;
    const float sx = x0 * rf, sy = x1 * rf, sz = x2 * rf;
    int ix = (int)sx; ix = ix < 0 ? 0 : (ix > rl - 2 ? rl - 2 : ix);
    int iy = (int)sy; iy = iy < 0 ? 0 : (iy > rl - 2 ? rl - 2 : iy);
    int iz = (int)sz; iz = iz < 0 ? 0 : (iz > rl - 2 ? rl - 2 : iz);
    p.ix = ix; p.iy = iy; p.iz = iz;
    p.fx = sx - (float)ix; p.fy = sy - (float)iy; p.fz = sz - (float)iz;
    return p;
}

__device__ __forceinline__ float2 blend8s(
    uint32_t c0, uint32_t c1, uint32_t c2, uint32_t c3,
    uint32_t c4, uint32_t c5, uint32_t c6, uint32_t c7,
    float fx, float fy, float fz)
{
    const float wx0 = 1.0f - fx, wx1 = fx;
    const float wy0 = 1.0f - fy, wy1 = fy;
    const float wz0 = 1.0f - fz, wz1 = fz;
    float w, f0 = 0.0f, f1 = 0.0f;
    w = wx0 * wy0 * wz0; f0 = fmaf(w, bf_lo(c0), f0); f1 = fmaf(w, bf_hi(c0), f1);
    w = wx1 * wy0 * wz0; f0 = fmaf(w, bf_lo(c1), f0); f1 = fmaf(w, bf_hi(c1), f1);
    w = wx0 * wy1 * wz0; f0 = fmaf(w, bf_lo(c2), f0); f1 = fmaf(w, bf_hi(c2), f1);
    w = wx1 * wy1 * wz0; f0 = fmaf(w, bf_lo(c3), f0); f1 = fmaf(w, bf_hi(c3), f1);
    w = wx0 * wy0 * wz1; f0 = fmaf(w, bf_lo(c4), f0); f1 = fmaf(w, bf_hi(c4), f1);
    w = wx1 * wy0 * wz1; f0 = fmaf(w, bf_lo(c5), f0); f1 = fmaf(w, bf_hi(c5), f1);
    w = wx0 * wy1 * wz1; f0 = fmaf(w, bf_lo(c6), f0); f1 = fmaf(w, bf_hi(c6), f1);
    w = wx1 * wy1 * wz1; f0 = fmaf(w, bf_lo(c7), f0); f1 = fmaf(w, bf_hi(c7), f1);
    float2 o; o.x = f0; o.y = f1;
    return o;
}

// ---------- phase 1: gather + trilinear blend, CHUNK-MAJOR output ----------
// Gather + XCD rebalance identical to r8 (295.8us, occ 75%, verified).
// Only change: feat layout [chunk][16][256] so phase 2 reads contiguous tiles.
// (r8 post-mortem: transpose read 16 streams 8MB apart -> ~1.3TB/s HBM;
// chunk-major makes both transpose sides pure linear streams.)
__global__ __launch_bounds__(256, 6) void hg_levels(
    const float* __restrict__ x,
    const uint32_t* __restrict__ tabF,   // [11, T] packed bf16x2 (levels 5..15)
    const uint32_t* __restrict__ tabD,   // cell tables (levels 0..4)
    float2* __restrict__ feat,           // [chunks, 16, 256]
    int N, Params P)
{
    const int xcd = blockIdx.x & 7;
    const int w   = blockIdx.x >> 3;
    const int ch  = P.chunks, D = P.don;

    int l, chunk;
    if (w < ch) { l = xcd; chunk = w; }
    else if (xcd < 3) {
        if (w < 2 * ch) { l = xcd + 8; chunk = w - ch; }
        else            { l = 13 + xcd; chunk = (ch - D) + (w - 2 * ch); } // donated tail
    } else if (xcd < 5) {
        if (w < 2 * ch) { l = xcd + 8; chunk = w - ch; } else return;
    } else {
        if (w < 2 * ch - D) { l = xcd + 8; chunk = w - ch; } else return;  // keeps first ch-D
    }

    const int n = chunk * 256 + threadIdx.x;
    if (n >= N) return;

    const int rl = P.res[l];
    const float rf = (float)(rl - 1);
    const Pt p = mk_pt(x[n * 3 + 0], x[n * 3 + 1], x[n * 3 + 2], rl, rf);

    float2 o;
    if (l < N_CELL) {
        // ---- cell gather: 2 aligned 16B lines ----
        const uint32_t* __restrict__ t = tabD + P.dOff[l];
        const int C = rl - 1;
        const uint32_t* cb = t + (size_t)((p.iz * C + p.iy) * C + p.ix) * 8;
        const uint4 q0 = *(const uint4*)cb;
        const uint4 q1 = *(const uint4*)(cb + 4);
        __builtin_amdgcn_sched_barrier(0);
        o = blend8s(q0.x, q0.y, q0.z, q0.w, q1.x, q1.y, q1.z, q1.w,
                    p.fx, p.fy, p.fz);
    } else {
        // ---- quad-hash gather: 4 aligned 16B lines + divergent extras ----
        const uint32_t* __restrict__ t = tabF + (size_t)(l - N_CELL) * T_SIZE;
        const uint32_t hx = (uint32_t)p.ix;
        const uint32_t dx = hx ^ (hx + 1u);
        const uint32_t y0 = (uint32_t)p.iy * PRIME1, y1 = y0 + PRIME1;
        const uint32_t z0 = (uint32_t)p.iz * PRIME2, z1 = z0 + PRIME2;
        const uint32_t i00 = (hx ^ y0 ^ z0) & T_MASK;
        const uint32_t i10 = (hx ^ y1 ^ z0) & T_MASK;
        const uint32_t i01 = (hx ^ y0 ^ z1) & T_MASK;
        const uint32_t i11 = (hx ^ y1 ^ z1) & T_MASK;
        const uint4 q00 = *(const uint4*)(t + (i00 & ~3u));
        const uint4 q10 = *(const uint4*)(t + (i10 & ~3u));
        const uint4 q01 = *(const uint4*)(t + (i01 & ~3u));
        const uint4 q11 = *(const uint4*)(t + (i11 & ~3u));
        // divergent second-x-corner loads (25% of lanes: ix%4==3)
        uint32_t s1 = 0, s3 = 0, s5 = 0, s7 = 0;
        const bool in4 = (dx < 4u);
        if (!in4) {
            s1 = t[(i00 ^ dx) & T_MASK];
            s3 = t[(i10 ^ dx) & T_MASK];
            s5 = t[(i01 ^ dx) & T_MASK];
            s7 = t[(i11 ^ dx) & T_MASK];
        }
        __builtin_amdgcn_sched_barrier(0);
        const uint32_t c0 = sel4(q00, i00 & 3u);
        const uint32_t c2 = sel4(q10, i10 & 3u);
        const uint32_t c4 = sel4(q01, i01 & 3u);
        const uint32_t c6 = sel4(q11, i11 & 3u);
        const uint32_t c1 = in4 ? sel4(q00, (i00 ^ dx) & 3u) : s1;
        const uint32_t c3 = in4 ? sel4(q10, (i10 ^ dx) & 3u) : s3;
        const uint32_t c5 = in4 ? sel4(q01, (i01 ^ dx) & 3u) : s5;
        const uint32_t c7 = in4 ? sel4(q11, (i11 ^ dx) & 3u) : s7;
        o = blend8s(c0, c1, c2, c3, c4, c5, c6, c7, p.fx, p.fy, p.fz);
    }

    // NT store (write-once stream, keeps pinned tables in L2). Chunk-major:
    // block writes 2KB contiguous, chunk tile [16][256] is contiguous 32KB.
    nt_store_f2(o, &feat[((size_t)chunk * 16 + l) * 256 + threadIdx.x]);
}

// ---------- phase 2: tile transpose [chunk][16][256] -> [N,16] ----------
// 1 block = 1 chunk = 256 points. Reads 32KB CONTIGUOUS, writes 32KB
// contiguous -> pure linear HBM streams both ways (r8 gap theory fix).
// LDS as f4v rows: b128 writes conflict-free; reads 16 unique addrs +
// 8-lane broadcast (~free).
__global__ __launch_bounds__(256) void hg_transpose(
    const float2* __restrict__ feat, f4v* __restrict__ out, int N)
{
    __shared__ f4v st4[N_LEVELS][130];     // 33.3KB; pad 130 spreads rows
    const int chunk = blockIdx.x;
    const int base = chunk * 256;
    const int t = threadIdx.x;
    const f4v* __restrict__ src = (const f4v*)feat + (size_t)chunk * 2048;
#pragma unroll
    for (int i = 0; i < 8; ++i) {
        const int idx = i * 256 + t;       // 0..2047 : f4v index in 32KB tile
        const int l = idx >> 7, j = idx & 127;   // row l, f4v j covers pts 2j,2j+1
        st4[l][j] = src[l * 128 + j];
    }
    __syncthreads();
#pragma unroll
    for (int i = 0; i < 8; ++i) {
        const int idx = i * 256 + t;       // 0..2047
        const int p = idx >> 3, k = idx & 7;
        const int n = base + p;
        if (n < N) {
            const f4v qa = st4[2 * k][p >> 1];
            const f4v qb = st4[2 * k + 1][p >> 1];
            const bool hi = (p & 1);
            f4v o;
            o.x = hi ? qa.z : qa.x; o.y = hi ? qa.w : qa.y;
            o.z = hi ? qb.z : qb.x; o.w = hi ? qb.w : qb.y;
            out[(size_t)n * 8 + k] = o;
        }
    }
}

// ---------- fallback: used only if ws is too small ----------
__global__ __launch_bounds__(256) void hg_fallback(
    const float* __restrict__ x, const float* __restrict__ emb,
    float* __restrict__ out, int N, Params P)
{
    const int gid = blockIdx.x * 256 + threadIdx.x;
    const int n = gid >> 4, l = gid & 15;
    if (n >= N) return;
    const int rl = P.res[l];
    const float rf = (float)(rl - 1);
    float sx = x[n * 3 + 0] * rf, sy = x[n * 3 + 1] * rf, sz = x[n * 3 + 2] * rf;
    int ix = (int)sx; ix = ix < 0 ? 0 : (ix > rl - 2 ? rl - 2 : ix);
    int iy = (int)sy; iy = iy < 0 ? 0 : (iy > rl - 2 ? rl - 2 : iy);
    int iz = (int)sz; iz = iz < 0 ? 0 : (iz > rl - 2 ? rl - 2 : iz);
    const float fx = sx - ix, fy = sy - iy, fz = sz - iz;
    const uint32_t hx0 = (uint32_t)ix, hx1 = hx0 + 1u;
    const uint32_t hy0 = (uint32_t)iy * PRIME1, hy1 = hy0 + PRIME1;
    const uint32_t hz0 = (uint32_t)iz * PRIME2, hz1 = hz0 + PRIME2;
    const float2* tab = (const float2*)emb + (size_t)l * T_SIZE;
    float2 e0 = tab[(hx0 ^ hy0 ^ hz0) & T_MASK], e1 = tab[(hx1 ^ hy0 ^ hz0) & T_MASK];
    float2 e2 = tab[(hx0 ^ hy1 ^ hz0) & T_MASK], e3 = tab[(hx1 ^ hy1 ^ hz0) & T_MASK];
    float2 e4 = tab[(hx0 ^ hy0 ^ hz1) & T_MASK], e5 = tab[(hx1 ^ hy0 ^ hz1) & T_MASK];
    float2 e6 = tab[(hx0 ^ hy1 ^ hz1) & T_MASK], e7 = tab[(hx1 ^ hy1 ^ hz1) & T_MASK];
    const float wx0 = 1.0f - fx, wx1 = fx, wy0 = 1.0f - fy, wy1 = fy, wz0 = 1.0f - fz, wz1 = fz;
    float w, f0 = 0.0f, f1 = 0.0f;
    w = wx0 * wy0 * wz0; f0 = fmaf(w, e0.x, f0); f1 = fmaf(w, e0.y, f1);
    w = wx1 * wy0 * wz0; f0 = fmaf(w, e1.x, f0); f1 = fmaf(w, e1.y, f1);
    w = wx0 * wy1 * wz0; f0 = fmaf(w, e2.x, f0); f1 = fmaf(w, e2.y, f1);
    w = wx1 * wy1 * wz0; f0 = fmaf(w, e3.x, f0); f1 = fmaf(w, e3.y, f1);
    w = wx0 * wy0 * wz1; f0 = fmaf(w, e4.x, f0); f1 = fmaf(w, e4.y, f1);
    w = wx1 * wy0 * wz1; f0 = fmaf(w, e5.x, f0); f1 = fmaf(w, e5.y, f1);
    w = wx0 * wy1 * wz1; f0 = fmaf(w, e6.x, f0); f1 = fmaf(w, e6.y, f1);
    w = wx1 * wy1 * wz1; f0 = fmaf(w, e7.x, f0); f1 = fmaf(w, e7.y, f1);
    float2 o; o.x = f0; o.y = f1;
    ((float2*)out)[(size_t)n * N_LEVELS + l] = o;
}

extern "C" void kernel_launch(void* const* d_in, const int* in_sizes, int n_in,
                              void* d_out, int out_size, void* d_ws, size_t ws_size,
                              hipStream_t stream) {
    const float* x   = (const float*)d_in[0];
    const float* emb = (const float*)d_in[1];
    const int N = in_sizes[0] / 3;

    // CPython-identical level resolutions (truncation-sensitive: 16*b^3 == 32)
    Params P;
    const double b = exp((log(512.0) - log(16.0)) / 15.0);
    for (int i = 0; i < N_LEVELS; ++i)
        P.res[i] = (int)(16.0 * pow(b, (double)i));

    // cell tables (levels 0..4)
    P.cellOffC[0] = 0;
    for (int l = 0; l < N_CELL; ++l) {
        const int C = P.res[l] - 1;
        P.cellOffC[l + 1] = P.cellOffC[l] + C * C * C;
    }
    P.cellTot = P.cellOffC[N_CELL];
    for (int l = 0; l < N_CELL; ++l) P.dOff[l] = P.cellOffC[l] * 8;

    P.chunks = (N + 255) / 256;
    P.don    = (P.chunks * 3) / 10;        // balance: 7+5a = 10-5a -> a = 0.3

    const size_t fine_bytes  = (size_t)N_HASH * T_SIZE * sizeof(uint32_t);        // 22 MB
    const size_t dense_bytes = ((size_t)P.cellTot * 8 * sizeof(uint32_t) + 255) & ~255ull; // ~3.7 MB
    const size_t feat_bytes  = (size_t)P.chunks * N_LEVELS * 256 * sizeof(float2); // 128 MB

    if (ws_size >= fine_bytes + dense_bytes + feat_bytes) {
        uint32_t* tabF = (uint32_t*)d_ws;
        uint32_t* tabD = (uint32_t*)((char*)d_ws + fine_bytes);
        float2*   feat = (float2*)((char*)d_ws + fine_bytes + dense_bytes);

        hipLaunchKernelGGL(hg_build_fine, dim3(N_HASH * T_SIZE / 256), dim3(256), 0, stream,
                           (const float2*)emb, tabF);
        hipLaunchKernelGGL(hg_build_cell, dim3((P.cellTot * 8 + 255) / 256), dim3(256), 0, stream,
                           (const float2*)emb, tabD, P);

        // grid: 8 XCD slots x (2*chunks + don) work indices; surplus blocks exit
        hipLaunchKernelGGL(hg_levels, dim3(8 * (2 * P.chunks + P.don)), dim3(256), 0, stream,
                           x, tabF, tabD, feat, N, P);

        hipLaunchKernelGGL(hg_transpose, dim3(P.chunks), dim3(256), 0, stream,
                           feat, (f4v*)d_out, N);
    } else {
        hipLaunchKernelGGL(hg_fallback, dim3((N * 16 + 255) / 256), dim3(256), 0, stream,
                           x, emb, (float*)d_out, N, P);
    }
}